// Round 4
// baseline (315.110 us; speedup 1.0000x reference)
//
#include <hip/hip_runtime.h>

typedef __attribute__((ext_vector_type(4))) float f32x4;
typedef __attribute__((ext_vector_type(8))) short s16x8;
typedef __attribute__((ext_vector_type(4))) unsigned short u16x4;
typedef __attribute__((ext_vector_type(8))) unsigned short u16x8;

#define DEVINL __device__ __forceinline__

constexpr int Bb = 2;
constexpr int Ss = 2048;
constexpr int Hh = 2048;
constexpr int NH = 16;
constexpr int HD = 128;
constexpr float ATT_SCALE = 0.08838834764831845f;   // 128^-0.5
constexpr float CEXP = ATT_SCALE * 1.44269504089f;  // scale * log2(e)
constexpr float INV_SCALE = 11.313708498984761f;    // 1/scale
constexpr float RAW_THR = 90.50966799f;             // 8/scale (defer-max threshold)

DEVINL unsigned short f2bf(float f) {
    unsigned u = __float_as_uint(f);
    u += 0x7FFFu + ((u >> 16) & 1u);
    return (unsigned short)(u >> 16);
}
DEVINL float bf2f(unsigned short h) { return __uint_as_float(((unsigned)h) << 16); }
DEVINL float fexp2(float x) { return __builtin_amdgcn_exp2f(x); }

// global -> LDS direct (16B per lane). Dest must be linear in lane order.
DEVINL void gl16(const void* g, void* l) {
    __builtin_amdgcn_global_load_lds((const __attribute__((address_space(1))) void*)g,
                                     (__attribute__((address_space(3))) void*)l, 16, 0, 0);
}

// ---------------- mask zero-scan ----------------
__global__ void zero_flag_k(int* f) { if (threadIdx.x == 0) *f = 0; }

__global__ void scan_mask_k(const float* __restrict__ m, int* __restrict__ flag) {
    size_t i = ((size_t)blockIdx.x * 256 + threadIdx.x) * 4;
    f32x4 v = *(const f32x4*)(m + i);
    int any = (v[0] != 0.f) || (v[1] != 0.f) || (v[2] != 0.f) || (v[3] != 0.f);
    if (__any(any)) { if ((threadIdx.x & 63) == 0) atomicOr(flag, 1); }
}

// ---------------- fp32 -> bf16 convert (hidden) ----------------
__global__ void convH_k(const float* __restrict__ x, unsigned short* __restrict__ y) {
    size_t i = (size_t)blockIdx.x * 256 + threadIdx.x;
    f32x4 a = *(const f32x4*)(x + i * 8);
    f32x4 b = *(const f32x4*)(x + i * 8 + 4);
    u16x8 o;
    o[0] = f2bf(a[0]); o[1] = f2bf(a[1]); o[2] = f2bf(a[2]); o[3] = f2bf(a[3]);
    o[4] = f2bf(b[0]); o[5] = f2bf(b[1]); o[6] = f2bf(b[2]); o[7] = f2bf(b[3]);
    *(u16x8*)(y + i * 8) = o;
}

// ---------------- fp32 -> bf16 transpose (weights: W[R][C] -> Wt[C][R]) ----------------
__global__ void convT_k(const float* __restrict__ W, unsigned short* __restrict__ Wt,
                        int R, int C) {
    __shared__ float tile[32][33];
    int c0 = blockIdx.x * 32, r0 = blockIdx.y * 32;
    int t = threadIdx.x;
    int rr = t >> 3, cc = (t & 7) * 4;
    f32x4 v = *(const f32x4*)(W + (size_t)(r0 + rr) * C + c0 + cc);
    tile[rr][cc + 0] = v[0]; tile[rr][cc + 1] = v[1];
    tile[rr][cc + 2] = v[2]; tile[rr][cc + 3] = v[3];
    __syncthreads();
    u16x4 o;
    o[0] = f2bf(tile[cc + 0][rr]); o[1] = f2bf(tile[cc + 1][rr]);
    o[2] = f2bf(tile[cc + 2][rr]); o[3] = f2bf(tile[cc + 3][rr]);
    *(u16x4*)(Wt + (size_t)(c0 + rr) * R + r0 + cc) = o;
}

// ---------------- GEMM 256x256, BK=64, 8 waves (2Mx4N), counted-vmcnt pipeline ------
// C[M][N] = A[M][K] * Bt[N][K]^T, bf16 in, MODE 0: bf16 out + fused RoPE; MODE 1: f32.
// LDS: buf[2] x (A 256x64 + B 256x64) bf16 = 128 KiB. 16 gl16/thread in flight;
// vmcnt(8) at each buffer consume point drains exactly that buffer's loads.
template<int MODE>
__global__ __launch_bounds__(512, 2)
void gemm256_k(const unsigned short* __restrict__ A, const unsigned short* __restrict__ Bt,
               float* __restrict__ Cf, unsigned short* __restrict__ Cb,
               int M, int N, int K) {
    __shared__ char lds[131072];
    int t = threadIdx.x, w = t >> 6, ln = t & 63, lr = ln & 15, lg = ln >> 4;
    int wm = w >> 2, wn = w & 3;
    int f = blockIdx.x, cpx = gridDim.x >> 3;
    int s = (f & 7) * cpx + (f >> 3);      // bijective XCD swizzle (grid % 8 == 0)
    int nbn = N >> 8;
    int nb = s % nbn, mb = s / nbn;
    int m0 = mb * 256, n0 = nb * 256;
    const char* Ab = (const char*)A;
    const char* Bbp = (const char*)Bt;

    f32x4 acc[8][4];
#pragma unroll
    for (int i = 0; i < 8; ++i)
#pragma unroll
        for (int j = 0; j < 4; ++j) { acc[i][j][0] = 0.f; acc[i][j][1] = 0.f; acc[i][j][2] = 0.f; acc[i][j][3] = 0.f; }

    // stage K-tile kt (64 cols) into buffer buf: 8 gl16/thread, lane-linear dest,
    // inverse-swizzled source column.
    auto STAGE = [&](int buf, int kt) {
        size_t k0 = (size_t)kt * 64;
        char* dA = lds + buf * 65536;
        char* dB = dA + 32768;
#pragma unroll
        for (int ld = 0; ld < 4; ++ld) {
            int ci = ld * 512 + t;
            int row = ci >> 3, cb = (ci & 7) << 4;
            int sc = cb ^ ((row & 7) << 4);
            gl16(Ab + ((size_t)(m0 + row) * K + k0) * 2 + sc, dA + ci * 16);
        }
#pragma unroll
        for (int ld = 0; ld < 4; ++ld) {
            int ci = ld * 512 + t;
            int row = ci >> 3, cb = (ci & 7) << 4;
            int sc = cb ^ ((row & 7) << 4);
            gl16(Bbp + ((size_t)(n0 + row) * K + k0) * 2 + sc, dB + ci * 16);
        }
    };

    const int NT = K >> 6;      // 32 K-tiles
    STAGE(0, 0);
    STAGE(1, 1);                // 16 loads in flight

    for (int it = 0; it < (NT >> 1); ++it) {
        int e = 2 * it;
#pragma unroll
        for (int half = 0; half < 2; ++half) {
            const char* Ax = lds + half * 65536;
            const char* Bx = Ax + 32768;
            // wait: this buffer's 8 loads are the oldest 8 of my 16 outstanding
            asm volatile("s_waitcnt vmcnt(8)" ::: "memory");
            __builtin_amdgcn_s_barrier();          // everyone's loads landed
            __builtin_amdgcn_sched_barrier(0);
            s16x8 af[8], bfr[4];
            // ---- k-step 0 ----
#pragma unroll
            for (int i = 0; i < 8; ++i) {
                int rowa = wm * 128 + i * 16 + lr;
                af[i] = *(const s16x8*)(Ax + rowa * 128 + ((lg * 16) ^ ((rowa & 7) << 4)));
            }
#pragma unroll
            for (int j = 0; j < 4; ++j) {
                int rowb = wn * 64 + j * 16 + lr;
                bfr[j] = *(const s16x8*)(Bx + rowb * 128 + ((lg * 16) ^ ((rowb & 7) << 4)));
            }
            asm volatile("s_waitcnt lgkmcnt(0)" ::: "memory");
            __builtin_amdgcn_sched_barrier(0);
            __builtin_amdgcn_s_setprio(1);
#pragma unroll
            for (int i = 0; i < 8; ++i)
#pragma unroll
                for (int j = 0; j < 4; ++j)
                    acc[i][j] = __builtin_amdgcn_mfma_f32_16x16x32_bf16(af[i], bfr[j], acc[i][j], 0, 0, 0);
            __builtin_amdgcn_s_setprio(0);
            // ---- k-step 1 ----
#pragma unroll
            for (int i = 0; i < 8; ++i) {
                int rowa = wm * 128 + i * 16 + lr;
                af[i] = *(const s16x8*)(Ax + rowa * 128 + ((64 + lg * 16) ^ ((rowa & 7) << 4)));
            }
#pragma unroll
            for (int j = 0; j < 4; ++j) {
                int rowb = wn * 64 + j * 16 + lr;
                bfr[j] = *(const s16x8*)(Bx + rowb * 128 + ((64 + lg * 16) ^ ((rowb & 7) << 4)));
            }
            asm volatile("s_waitcnt lgkmcnt(0)" ::: "memory");
            __builtin_amdgcn_sched_barrier(0);
            __builtin_amdgcn_s_barrier();          // all reads of this buffer complete
            __builtin_amdgcn_sched_barrier(0);
            int stg = e + 2 + half;                // re-stage this buffer 2 tiles ahead
            if (stg >= NT) stg -= 2;               // tail: restage current (never read)
            STAGE(half, stg);
            __builtin_amdgcn_s_setprio(1);
#pragma unroll
            for (int i = 0; i < 8; ++i)
#pragma unroll
                for (int j = 0; j < 4; ++j)
                    acc[i][j] = __builtin_amdgcn_mfma_f32_16x16x32_bf16(af[i], bfr[j], acc[i][j], 0, 0, 0);
            __builtin_amdgcn_s_setprio(0);
        }
    }

    // fused RoPE (QKV gemm only): head-dim offset = (wn*64 + j*16 + lr) & 127;
    // waves wn 0,2 hold the rotary pair as (j=0 -> d, j=1 -> d+16).
    if (MODE == 0 && n0 < 4096 && (wn & 1) == 0) {
        float invf = fexp2((float)lr * -0.83048202372f); // 10000^(-lr/16)
#pragma unroll
        for (int i = 0; i < 8; ++i)
#pragma unroll
            for (int r = 0; r < 4; ++r) {
                int srow = (m0 + wm * 128 + i * 16 + lg * 4 + r) & (Ss - 1);
                float sn, cs;
                sincosf((float)srow * invf, &sn, &cs);
                float x1 = acc[i][0][r], x2 = acc[i][1][r];
                acc[i][0][r] = x1 * cs - x2 * sn;
                acc[i][1][r] = x2 * cs + x1 * sn;
            }
    }

    // epilogue: C/D layout col=l&15, row=(l>>4)*4+r
#pragma unroll
    for (int i = 0; i < 8; ++i)
#pragma unroll
        for (int j = 0; j < 4; ++j)
#pragma unroll
            for (int r = 0; r < 4; ++r) {
                int gr = m0 + wm * 128 + i * 16 + lg * 4 + r;
                int gc = n0 + wn * 64 + j * 16 + lr;
                float vv = acc[i][j][r];
                if (MODE == 1) Cf[(size_t)gr * N + gc] = vv;
                else           Cb[(size_t)gr * N + gc] = f2bf(vv);
            }
}

// ---------------- V transpose: qkv v-part -> Vt[bh][d][s] ----------------
__global__ void vtrans_k(const unsigned short* __restrict__ qkv, unsigned short* __restrict__ Vt) {
    __shared__ unsigned short tile[64][40];
    int bh = blockIdx.x; int b = bh >> 4, h = bh & 15;
    int s0 = blockIdx.y * 64, d0 = blockIdx.z * 32;
    int t = threadIdx.x;
    int r = t >> 2, c8 = (t & 3) * 8;
    u16x8 v = *(const u16x8*)(qkv + ((size_t)(b * Ss + s0 + r)) * 6144 + 4096 + h * 128 + d0 + c8);
#pragma unroll
    for (int e = 0; e < 8; ++e) tile[r][c8 + e] = v[e];
    __syncthreads();
    int dr = t >> 3, sc = (t & 7) * 8;
    u16x8 o;
#pragma unroll
    for (int e = 0; e < 8; ++e) o[e] = tile[sc + e][dr];
    *(u16x8*)(Vt + ((size_t)bh * HD + d0 + dr) * Ss + s0 + sc) = o;
}

// ---------------- flash attention ----------------
// 512 blocks (32 bh x 16 qt), 512 thr = 8 waves x 16 q-rows, KVBLK=64.
// Swapped QK^T: S^T = mfma(K, Q) -> lane owns q = lane&15; in-register softmax.
__global__ __launch_bounds__(512)
void attn_k(const unsigned short* __restrict__ qkv, const unsigned short* __restrict__ Vt,
            const float* __restrict__ mask, unsigned short* __restrict__ ctxb,
            const int* __restrict__ flag) {
    __shared__ char ldsK[64 * 256];            // [64 kk][128 d] bf16, swizzled
    __shared__ char ldsV[128 * 128];           // [128 d][64 kk] bf16, swizzled
    __shared__ unsigned short ldsP[8][1024];   // per-wave P [16 q][64 kk], swizzled
    int f = blockIdx.x;
    int swzb = (f & 7) * 64 + (f >> 3);        // XCD swizzle: 16 qt of 4 bh per XCD chunk
    int bh = swzb >> 4, qt = swzb & 15;
    int b = bh >> 4, h = bh & 15;
    int t = threadIdx.x, w = t >> 6, ln = t & 63, lr = ln & 15, lg = ln >> 4;
    int useMask = *flag;
    int qw0 = qt * 128 + w * 16;
    const char* qkvB = (const char*)qkv;
    const char* VtB = (const char*)Vt;

    // Q fragments (B-operand): lane holds Q[q=qw0+lr][d = kc*32 + lg*8 + e]
    s16x8 qf[4];
    size_t qbase = ((size_t)(b * Ss + qw0 + lr)) * 6144 + h * 128;
#pragma unroll
    for (int kc = 0; kc < 4; ++kc) qf[kc] = *(const s16x8*)(qkv + qbase + kc * 32 + lg * 8);

    float mr = -3e38f, lsum = 0.f;  // per-lane, q-row = lane&15, raw score units
    f32x4 ctxa[8];
#pragma unroll
    for (int dn = 0; dn < 8; ++dn) { ctxa[dn][0] = 0.f; ctxa[dn][1] = 0.f; ctxa[dn][2] = 0.f; ctxa[dn][3] = 0.f; }
    const float* mrow = mask + (size_t)b * Ss * Ss;

    for (int kk0 = 0; kk0 < Ss; kk0 += 64) {
        __syncthreads();
        // stage K (1024 chunks, 256B rows) + V (1024 chunks, 128B rows) via global_load_lds
#pragma unroll
        for (int c = 0; c < 2; ++c) {
            int ci = c * 512 + t;
            int krow = ci >> 4, kcb = (ci & 15) << 4;
            gl16(qkvB + (((size_t)(b * Ss + kk0 + krow)) * 6144 + 2048 + h * 128) * 2 + (kcb ^ ((krow & 7) << 4)),
                 ldsK + ci * 16);
            int vrow = ci >> 3, vcb = (ci & 7) << 4;
            gl16(VtB + (((size_t)(bh * 128 + vrow)) * 2048 + kk0) * 2 + (vcb ^ ((vrow & 7) << 4)),
                 ldsV + ci * 16);
        }
        __syncthreads();

        // S^T[kk][q] = K·Q^T : per n, lane holds kk = n*16 + lg*4 + r, q = lr
        f32x4 st[4];
#pragma unroll
        for (int n = 0; n < 4; ++n) {
            f32x4 sacc = {0.f, 0.f, 0.f, 0.f};
            const char* kb = ldsK + (n * 16 + lr) * 256;
            int sw = (lr & 7) << 4;
#pragma unroll
            for (int kc = 0; kc < 4; ++kc) {
                s16x8 kf = *(const s16x8*)(kb + ((kc * 64 + lg * 16) ^ sw));
                sacc = __builtin_amdgcn_mfma_f32_16x16x32_bf16(kf, qf[kc], sacc, 0, 0, 0);
            }
            st[n] = sacc;
        }
        if (useMask) {
#pragma unroll
            for (int n = 0; n < 4; ++n)
#pragma unroll
                for (int r = 0; r < 4; ++r)
                    st[n][r] += mrow[(size_t)(qw0 + lr) * Ss + kk0 + n * 16 + lg * 4 + r] * INV_SCALE;
        }
        // row max for q = lr (in-lane 16 values + reduce over lg via xor 16,32)
        float pmax = st[0][0];
#pragma unroll
        for (int n = 0; n < 4; ++n)
#pragma unroll
            for (int r = 0; r < 4; ++r) pmax = fmaxf(pmax, st[n][r]);
        pmax = fmaxf(pmax, __shfl_xor(pmax, 16));
        pmax = fmaxf(pmax, __shfl_xor(pmax, 32));
        // defer-max: rescale only if max grew by > 8/scale (raw units)
        bool need = pmax > mr + RAW_THR;
        if (__any(need)) {
            float mn = fmaxf(mr, pmax);
            float al = fexp2((mr - mn) * CEXP);
            mr = mn;
            lsum *= al;
            float a0 = __shfl(al, lg * 4 + 0), a1 = __shfl(al, lg * 4 + 1);
            float a2 = __shfl(al, lg * 4 + 2), a3 = __shfl(al, lg * 4 + 3);
#pragma unroll
            for (int dn = 0; dn < 8; ++dn) {
                ctxa[dn][0] *= a0; ctxa[dn][1] *= a1; ctxa[dn][2] *= a2; ctxa[dn][3] *= a3;
            }
        }
        float mC = mr * CEXP;
        float rs = 0.f;
        u16x4 pk[4];
#pragma unroll
        for (int n = 0; n < 4; ++n)
#pragma unroll
            for (int r = 0; r < 4; ++r) {
                float p = fexp2(st[n][r] * CEXP - mC);
                rs += p;
                pk[n][r] = f2bf(p);
            }
        rs += __shfl_xor(rs, 16);
        rs += __shfl_xor(rs, 32);
        lsum += rs;
        // P -> per-wave LDS [q=lr][kk], packed b64 writes, XOR-swizzled rows
        char* pw = (char*)ldsP[w];
        int swp = (lr & 7) << 4;
#pragma unroll
        for (int n = 0; n < 4; ++n)
            *(u16x4*)(pw + lr * 128 + ((32 * n + 8 * lg) ^ swp)) = pk[n];
        asm volatile("s_waitcnt lgkmcnt(0)" ::: "memory");
        s16x8 pa[2];
#pragma unroll
        for (int c2 = 0; c2 < 2; ++c2)
            pa[c2] = *(const s16x8*)(pw + lr * 128 + ((64 * c2 + 16 * lg) ^ swp));
        // PV: ctx[q][d] += P[q][kk] * V[kk][d]
#pragma unroll
        for (int dn = 0; dn < 8; ++dn) {
            const char* vb = ldsV + (dn * 16 + lr) * 128;
#pragma unroll
            for (int c2 = 0; c2 < 2; ++c2) {
                s16x8 vf = *(const s16x8*)(vb + ((c2 * 64 + lg * 16) ^ swp));
                ctxa[dn] = __builtin_amdgcn_mfma_f32_16x16x32_bf16(pa[c2], vf, ctxa[dn], 0, 0, 0);
            }
        }
    }
    // epilogue: divide by lsum (fetch per-row via shfl), write ctx bf16
    float l0 = 1.f / __shfl(lsum, lg * 4 + 0), l1 = 1.f / __shfl(lsum, lg * 4 + 1);
    float l2 = 1.f / __shfl(lsum, lg * 4 + 2), l3 = 1.f / __shfl(lsum, lg * 4 + 3);
#pragma unroll
    for (int dn = 0; dn < 8; ++dn) {
        size_t base = ((size_t)(b * Ss + qw0)) * Hh + h * 128 + dn * 16 + lr;
        ctxb[base + (size_t)(lg * 4 + 0) * Hh] = f2bf(ctxa[dn][0] * l0);
        ctxb[base + (size_t)(lg * 4 + 1) * Hh] = f2bf(ctxa[dn][1] * l1);
        ctxb[base + (size_t)(lg * 4 + 2) * Hh] = f2bf(ctxa[dn][2] * l2);
        ctxb[base + (size_t)(lg * 4 + 3) * Hh] = f2bf(ctxa[dn][3] * l3);
    }
}

extern "C" void kernel_launch(void* const* d_in, const int* in_sizes, int n_in,
                              void* d_out, int out_size, void* d_ws, size_t ws_size,
                              hipStream_t stream) {
    (void)in_sizes; (void)n_in; (void)out_size; (void)ws_size;
    const float* hidden = (const float*)d_in[0];
    const float* mask   = (const float*)d_in[1];
    const float* Wqkv   = (const float*)d_in[2];
    const float* Wout   = (const float*)d_in[3];
    float* out = (float*)d_out;

    char* ws = (char*)d_ws;
    size_t off = 0;
    auto alloc = [&](size_t bytes) { char* p = ws + off; off += (bytes + 255) & ~(size_t)255; return p; };
    unsigned short* hbf   = (unsigned short*)alloc((size_t)8388608 * 2);   // hidden bf16; later aliased as ctx
    unsigned short* wqkvT = (unsigned short*)alloc((size_t)12582912 * 2);  // (6144,2048)
    unsigned short* woutT = (unsigned short*)alloc((size_t)4194304 * 2);   // (2048,2048)
    unsigned short* qkv   = (unsigned short*)alloc((size_t)25165824 * 2);  // (4096,6144)
    unsigned short* Vt    = (unsigned short*)alloc((size_t)8388608 * 2);   // (32,128,2048)
    int* flag             = (int*)alloc(256);
    unsigned short* ctx = hbf; // alias: hidden bf16 dead after QKV GEMM

    zero_flag_k<<<1, 64, 0, stream>>>(flag);
    scan_mask_k<<<2048, 256, 0, stream>>>(mask, flag);
    convH_k<<<4096, 256, 0, stream>>>(hidden, hbf);
    convT_k<<<dim3(192, 64), 256, 0, stream>>>(Wqkv, wqkvT, 2048, 6144);
    convT_k<<<dim3(64, 64), 256, 0, stream>>>(Wout, woutT, 2048, 2048);
    gemm256_k<0><<<384, 512, 0, stream>>>(hbf, wqkvT, nullptr, qkv, 4096, 6144, 2048);
    vtrans_k<<<dim3(32, 32, 4), 256, 0, stream>>>(qkv, Vt);
    attn_k<<<512, 512, 0, stream>>>(qkv, Vt, mask, ctx, flag);
    gemm256_k<1><<<128, 512, 0, stream>>>(ctx, woutT, out, nullptr, 4096, 2048, 2048);
}

// Round 6
// 313.766 us; speedup vs baseline: 1.0043x; 1.0043x over previous
//
#include <hip/hip_runtime.h>

typedef __attribute__((ext_vector_type(4))) float f32x4;
typedef __attribute__((ext_vector_type(8))) short s16x8;
typedef __attribute__((ext_vector_type(4))) unsigned short u16x4;
typedef __attribute__((ext_vector_type(8))) unsigned short u16x8;

#define DEVINL __device__ __forceinline__

constexpr int Bb = 2;
constexpr int Ss = 2048;
constexpr int Hh = 2048;
constexpr int NH = 16;
constexpr int HD = 128;
constexpr float ATT_SCALE = 0.08838834764831845f;   // 128^-0.5
constexpr float CEXP = ATT_SCALE * 1.44269504089f;  // scale * log2(e)
constexpr float INV_SCALE = 11.313708498984761f;    // 1/scale
constexpr float RAW_THR = 90.50966799f;             // 8/scale (defer-max threshold)

DEVINL unsigned short f2bf(float f) {
    unsigned u = __float_as_uint(f);
    u += 0x7FFFu + ((u >> 16) & 1u);
    return (unsigned short)(u >> 16);
}
DEVINL float bf2f(unsigned short h) { return __uint_as_float(((unsigned)h) << 16); }
DEVINL float fexp2(float x) { return __builtin_amdgcn_exp2f(x); }

// global -> LDS direct (16B per lane). Dest must be linear in lane order.
DEVINL void gl16(const void* g, void* l) {
    __builtin_amdgcn_global_load_lds((const __attribute__((address_space(1))) void*)g,
                                     (__attribute__((address_space(3))) void*)l, 16, 0, 0);
}

// ---------------- mask zero-scan ----------------
__global__ void zero_flag_k(int* f) { if (threadIdx.x == 0) *f = 0; }

__global__ void scan_mask_k(const float* __restrict__ m, int* __restrict__ flag) {
    size_t i = ((size_t)blockIdx.x * 256 + threadIdx.x) * 4;
    f32x4 v = *(const f32x4*)(m + i);
    int any = (v[0] != 0.f) || (v[1] != 0.f) || (v[2] != 0.f) || (v[3] != 0.f);
    if (__any(any)) { if ((threadIdx.x & 63) == 0) atomicOr(flag, 1); }
}

// ---------------- fp32 -> bf16 convert (hidden) ----------------
__global__ void convH_k(const float* __restrict__ x, unsigned short* __restrict__ y) {
    size_t i = (size_t)blockIdx.x * 256 + threadIdx.x;
    f32x4 a = *(const f32x4*)(x + i * 8);
    f32x4 b = *(const f32x4*)(x + i * 8 + 4);
    u16x8 o;
    o[0] = f2bf(a[0]); o[1] = f2bf(a[1]); o[2] = f2bf(a[2]); o[3] = f2bf(a[3]);
    o[4] = f2bf(b[0]); o[5] = f2bf(b[1]); o[6] = f2bf(b[2]); o[7] = f2bf(b[3]);
    *(u16x8*)(y + i * 8) = o;
}

// ---------------- fp32 -> bf16 transpose (weights: W[R][C] -> Wt[C][R]) ----------------
__global__ void convT_k(const float* __restrict__ W, unsigned short* __restrict__ Wt,
                        int R, int C) {
    __shared__ float tile[32][33];
    int c0 = blockIdx.x * 32, r0 = blockIdx.y * 32;
    int t = threadIdx.x;
    int rr = t >> 3, cc = (t & 7) * 4;
    f32x4 v = *(const f32x4*)(W + (size_t)(r0 + rr) * C + c0 + cc);
    tile[rr][cc + 0] = v[0]; tile[rr][cc + 1] = v[1];
    tile[rr][cc + 2] = v[2]; tile[rr][cc + 3] = v[3];
    __syncthreads();
    u16x4 o;
    o[0] = f2bf(tile[cc + 0][rr]); o[1] = f2bf(tile[cc + 1][rr]);
    o[2] = f2bf(tile[cc + 2][rr]); o[3] = f2bf(tile[cc + 3][rr]);
    *(u16x4*)(Wt + (size_t)(c0 + rr) * R + r0 + cc) = o;
}

// ================== 256x256 8-phase GEMM (QKV, fused RoPE) ==================
// C[M][N] = A[M][K] * Bt[N][K]^T bf16; BK=64; 8 waves (2M x 4N); dbuf LDS 128K.
// Regions: buf{0,1} x {A,B} x khalf{0,1}, each 256 rows x 32 cols bf16 (64B rows,
// 16 KiB). Per phase: ds_read subtile + stage one half-region (2 gl16/thread) +
// barrier + lgkm(0) + 16 MFMA + counted vmcnt (8/8/4 at p4/p6/p8, never 0).
#define PH(buf, kh, ih, sbuf, sX, skh, st, vm)                                    \
  {                                                                               \
    const char* Ar = lds + (buf)*65536 + (kh)*16384;                              \
    const char* Br = lds + (buf)*65536 + 32768 + (kh)*16384;                      \
    s16x8 af[4];                                                                  \
    if ((ih) == 0) {                                                              \
      _Pragma("unroll")                                                           \
      for (int j = 0; j < 4; ++j)                                                 \
        bfr[j] = *(const s16x8*)(Br + (wn*64 + j*16 + lr)*64 + lg*16);            \
    }                                                                             \
    _Pragma("unroll")                                                             \
    for (int i = 0; i < 4; ++i)                                                   \
      af[i] = *(const s16x8*)(Ar + (wm*128 + (ih)*64 + i*16 + lr)*64 + lg*16);    \
    STG(sbuf, sX, skh, st);                                                       \
    __builtin_amdgcn_s_barrier();                                                 \
    __builtin_amdgcn_sched_barrier(0);                                            \
    asm volatile("s_waitcnt lgkmcnt(0)" ::: "memory");                            \
    __builtin_amdgcn_sched_barrier(0);                                            \
    __builtin_amdgcn_s_setprio(1);                                                \
    _Pragma("unroll")                                                             \
    for (int i = 0; i < 4; ++i)                                                   \
      _Pragma("unroll")                                                           \
      for (int j = 0; j < 4; ++j)                                                 \
        acc[(ih)*4 + i][j] = __builtin_amdgcn_mfma_f32_16x16x32_bf16(             \
            af[i], bfr[j], acc[(ih)*4 + i][j], 0, 0, 0);                          \
    __builtin_amdgcn_s_setprio(0);                                                \
    if ((vm) == 8) { asm volatile("s_waitcnt vmcnt(8)" ::: "memory"); }           \
    if ((vm) == 4) { asm volatile("s_waitcnt vmcnt(4)" ::: "memory"); }           \
    __builtin_amdgcn_sched_barrier(0);                                            \
    __builtin_amdgcn_s_barrier();                                                 \
    __builtin_amdgcn_sched_barrier(0);                                            \
  }

template<int MODE>
__global__ __launch_bounds__(512, 2)
void gemm256_k(const unsigned short* __restrict__ A, const unsigned short* __restrict__ Bt,
               float* __restrict__ Cf, unsigned short* __restrict__ Cb,
               int M, int N, int K) {
    __shared__ char lds[131072];
    int t = threadIdx.x, w = t >> 6, ln = t & 63, lr = ln & 15, lg = ln >> 4;
    int wm = w >> 2, wn = w & 3;
    int f = blockIdx.x, cpx = gridDim.x >> 3;
    int s = (f & 7) * cpx + (f >> 3);      // bijective XCD swizzle (grid % 8 == 0)
    int nbn = N >> 8;
    int nb = s % nbn, mb = s / nbn;
    int m0 = mb * 256, n0 = nb * 256;
    const char* Ab = (const char*)A;
    const char* Bbp = (const char*)Bt;

    f32x4 acc[8][4];
#pragma unroll
    for (int i = 0; i < 8; ++i)
#pragma unroll
        for (int j = 0; j < 4; ++j) { acc[i][j][0] = 0.f; acc[i][j][1] = 0.f; acc[i][j][2] = 0.f; acc[i][j][3] = 0.f; }

    // stage half-region (sbuf, sX, skh) from K-tile kt: 2 gl16/thread = 16 KiB
    auto STG = [&](int sbuf, int sX, int skh, int kt) {
        char* dst = lds + sbuf * 65536 + sX * 32768 + skh * 16384;
        const char* src = sX ? Bbp : Ab;
        int rbase = sX ? n0 : m0;
        size_t kcol = (size_t)kt * 64 + skh * 32;
#pragma unroll
        for (int ld = 0; ld < 2; ++ld) {
            int ci = ld * 512 + t;
            int row = ci >> 2, sl = ci & 3;
            gl16(src + ((size_t)(rbase + row) * K + kcol) * 2 + sl * 16, dst + ci * 16);
        }
    };

    const int NT = K >> 6;
    // prologue: tile0 all 4 regions of buf0, tile1 k0-regions of buf1 (12 loads)
    STG(0, 0, 0, 0); STG(0, 1, 0, 0); STG(0, 0, 1, 0); STG(0, 1, 1, 0);
    STG(1, 0, 0, 1); STG(1, 1, 0, 1);
    asm volatile("s_waitcnt vmcnt(4)" ::: "memory");   // buf0 fully landed
    __builtin_amdgcn_sched_barrier(0);
    __builtin_amdgcn_s_barrier();
    __builtin_amdgcn_sched_barrier(0);

    s16x8 bfr[4];
    for (int it = 0; it < (NT >> 1); ++it) {
        int e = it * 2;
        int t2 = (e + 2 < NT) ? e + 2 : e;       // clamp: overwrites consumed region
        int t3 = (e + 3 < NT) ? e + 3 : e + 1;
        PH(0, 0, 0,  1, 0, 1, e + 1, 0)   // p1: b1.A.k1 <- tile e+1
        PH(0, 0, 1,  1, 1, 1, e + 1, 0)   // p2: b1.B.k1
        PH(0, 1, 0,  0, 0, 0, t2,    0)   // p3: b0.A.k0 <- tile e+2
        PH(0, 1, 1,  0, 1, 0, t2,    8)   // p4 (+vmcnt8: b1.k0 landed)
        PH(1, 0, 0,  0, 0, 1, t2,    0)   // p5: b0.A.k1
        PH(1, 0, 1,  0, 1, 1, t2,    8)   // p6 (+vmcnt8: b1.k1 landed)
        PH(1, 1, 0,  1, 0, 0, t3,    0)   // p7: b1.A.k0 <- tile e+3
        PH(1, 1, 1,  1, 1, 0, t3,    4)   // p8 (+vmcnt4: b0 next tile landed)
    }
    asm volatile("s_waitcnt vmcnt(0)" ::: "memory");   // drain before endpgm

    // fused RoPE (QKV gemm only): waves wn in {0,2} hold the rotary pair as
    // (j=0 -> head-dim lr, j=1 -> lr+16).
    if (MODE == 0 && n0 < 4096 && (wn & 1) == 0) {
        float invf = fexp2((float)lr * -0.83048202372f); // 10000^(-lr/16)
#pragma unroll
        for (int i = 0; i < 8; ++i)
#pragma unroll
            for (int r = 0; r < 4; ++r) {
                int srow = (m0 + wm * 128 + i * 16 + lg * 4 + r) & (Ss - 1);
                float sn, cs;
                sincosf((float)srow * invf, &sn, &cs);
                float x1 = acc[i][0][r], x2 = acc[i][1][r];
                acc[i][0][r] = x1 * cs - x2 * sn;
                acc[i][1][r] = x2 * cs + x1 * sn;
            }
    }

    // epilogue: C/D layout col=l&15, row=(l>>4)*4+r
#pragma unroll
    for (int i = 0; i < 8; ++i)
#pragma unroll
        for (int j = 0; j < 4; ++j)
#pragma unroll
            for (int r = 0; r < 4; ++r) {
                int gr = m0 + wm * 128 + i * 16 + lg * 4 + r;
                int gc = n0 + wn * 64 + j * 16 + lr;
                float vv = acc[i][j][r];
                if (MODE == 1) Cf[(size_t)gr * N + gc] = vv;
                else           Cb[(size_t)gr * N + gc] = f2bf(vv);
            }
}

// ================== 128x128 GEMM (out-proj; proven round-3 kernel) ==================
template<int MODE>
__global__ __launch_bounds__(256)
void gemm_bt_k(const unsigned short* __restrict__ A, const unsigned short* __restrict__ Bt,
               float* __restrict__ Cf, unsigned short* __restrict__ Cb,
               int M, int N, int K) {
    __shared__ char lds[128 * 64 * 2 * 2];
    char* As = lds;
    char* Bs = lds + 128 * 64 * 2;
    int t = threadIdx.x, w = t >> 6, ln = t & 63, lr = ln & 15, lg = ln >> 4;
    int f = blockIdx.x;
    int cpx = gridDim.x >> 3;
    int s = (f & 7) * cpx + (f >> 3);
    int nbn = N >> 7;
    int nb = s % nbn, mb = s / nbn;
    int m0 = mb * 128, n0 = nb * 128;
    int wr = w >> 1, wc = w & 1;
    const char* Abt = (const char*)A;
    const char* Bbt = (const char*)Bt;

    f32x4 acc[4][4];
#pragma unroll
    for (int i = 0; i < 4; ++i)
#pragma unroll
        for (int j = 0; j < 4; ++j) { acc[i][j][0] = 0.f; acc[i][j][1] = 0.f; acc[i][j][2] = 0.f; acc[i][j][3] = 0.f; }

    for (int k0 = 0; k0 < K; k0 += 64) {
        __syncthreads();
#pragma unroll
        for (int vv = 0; vv < 4; ++vv) {
            int ci = vv * 256 + t;
            int row = ci >> 3, cb = (ci & 7) << 4;
            int sc = cb ^ ((row & 7) << 4);
            gl16(Abt + ((size_t)(m0 + row) * K + k0) * 2 + sc, As + ci * 16);
            gl16(Bbt + ((size_t)(n0 + row) * K + k0) * 2 + sc, Bs + ci * 16);
        }
        __syncthreads();
#pragma unroll
        for (int kc = 0; kc < 2; ++kc) {
            s16x8 af[4], bfr[4];
#pragma unroll
            for (int i = 0; i < 4; ++i) {
                int rowa = wr * 64 + i * 16 + lr;
                af[i] = *(const s16x8*)(As + rowa * 128 + ((kc * 64 + lg * 16) ^ ((rowa & 7) << 4)));
                int rowb = wc * 64 + i * 16 + lr;
                bfr[i] = *(const s16x8*)(Bs + rowb * 128 + ((kc * 64 + lg * 16) ^ ((rowb & 7) << 4)));
            }
#pragma unroll
            for (int i = 0; i < 4; ++i)
#pragma unroll
                for (int j = 0; j < 4; ++j)
                    acc[i][j] = __builtin_amdgcn_mfma_f32_16x16x32_bf16(af[i], bfr[j], acc[i][j], 0, 0, 0);
        }
    }
#pragma unroll
    for (int i = 0; i < 4; ++i)
#pragma unroll
        for (int j = 0; j < 4; ++j)
#pragma unroll
            for (int r = 0; r < 4; ++r) {
                int gr = m0 + wr * 64 + i * 16 + lg * 4 + r;
                int gc = n0 + wc * 64 + j * 16 + lr;
                float vv = acc[i][j][r];
                if (MODE == 1) Cf[(size_t)gr * N + gc] = vv;
                else           Cb[(size_t)gr * N + gc] = f2bf(vv);
            }
}

// ---------------- V transpose: qkv v-part -> Vt[bh][d][s] ----------------
__global__ void vtrans_k(const unsigned short* __restrict__ qkv, unsigned short* __restrict__ Vt) {
    __shared__ unsigned short tile[64][40];
    int bh = blockIdx.x; int b = bh >> 4, h = bh & 15;
    int s0 = blockIdx.y * 64, d0 = blockIdx.z * 32;
    int t = threadIdx.x;
    int r = t >> 2, c8 = (t & 3) * 8;
    u16x8 v = *(const u16x8*)(qkv + ((size_t)(b * Ss + s0 + r)) * 6144 + 4096 + h * 128 + d0 + c8);
#pragma unroll
    for (int e = 0; e < 8; ++e) tile[r][c8 + e] = v[e];
    __syncthreads();
    int dr = t >> 3, sc = (t & 7) * 8;
    u16x8 o;
#pragma unroll
    for (int e = 0; e < 8; ++e) o[e] = tile[sc + e][dr];
    *(u16x8*)(Vt + ((size_t)bh * HD + d0 + dr) * Ss + s0 + sc) = o;
}

// ---------------- flash attention ----------------
// 512 blocks (32 bh x 16 qt), 512 thr = 8 waves x 16 q-rows, KVBLK=64.
// Swapped QK^T: S^T = mfma(K, Q) -> lane owns q = lane&15; in-register softmax.
__global__ __launch_bounds__(512)
void attn_k(const unsigned short* __restrict__ qkv, const unsigned short* __restrict__ Vt,
            const float* __restrict__ mask, unsigned short* __restrict__ ctxb,
            const int* __restrict__ flag) {
    __shared__ char ldsK[64 * 256];            // [64 kk][128 d] bf16, swizzled
    __shared__ char ldsV[128 * 128];           // [128 d][64 kk] bf16, swizzled
    __shared__ unsigned short ldsP[8][1024];   // per-wave P [16 q][64 kk], swizzled
    int f = blockIdx.x;
    int swzb = (f & 7) * 64 + (f >> 3);        // XCD swizzle
    int bh = swzb >> 4, qt = swzb & 15;
    int b = bh >> 4, h = bh & 15;
    int t = threadIdx.x, w = t >> 6, ln = t & 63, lr = ln & 15, lg = ln >> 4;
    int useMask = *flag;
    int qw0 = qt * 128 + w * 16;
    const char* qkvB = (const char*)qkv;
    const char* VtB = (const char*)Vt;

    s16x8 qf[4];
    size_t qbase = ((size_t)(b * Ss + qw0 + lr)) * 6144 + h * 128;
#pragma unroll
    for (int kc = 0; kc < 4; ++kc) qf[kc] = *(const s16x8*)(qkv + qbase + kc * 32 + lg * 8);

    float mr = -3e38f, lsum = 0.f;
    f32x4 ctxa[8];
#pragma unroll
    for (int dn = 0; dn < 8; ++dn) { ctxa[dn][0] = 0.f; ctxa[dn][1] = 0.f; ctxa[dn][2] = 0.f; ctxa[dn][3] = 0.f; }
    const float* mrow = mask + (size_t)b * Ss * Ss;

    for (int kk0 = 0; kk0 < Ss; kk0 += 64) {
        __syncthreads();
#pragma unroll
        for (int c = 0; c < 2; ++c) {
            int ci = c * 512 + t;
            int krow = ci >> 4, kcb = (ci & 15) << 4;
            gl16(qkvB + (((size_t)(b * Ss + kk0 + krow)) * 6144 + 2048 + h * 128) * 2 + (kcb ^ ((krow & 7) << 4)),
                 ldsK + ci * 16);
            int vrow = ci >> 3, vcb = (ci & 7) << 4;
            gl16(VtB + (((size_t)(bh * 128 + vrow)) * 2048 + kk0) * 2 + (vcb ^ ((vrow & 7) << 4)),
                 ldsV + ci * 16);
        }
        __syncthreads();

        f32x4 st[4];
#pragma unroll
        for (int n = 0; n < 4; ++n) {
            f32x4 sacc = {0.f, 0.f, 0.f, 0.f};
            const char* kb = ldsK + (n * 16 + lr) * 256;
            int sw = (lr & 7) << 4;
#pragma unroll
            for (int kc = 0; kc < 4; ++kc) {
                s16x8 kf = *(const s16x8*)(kb + ((kc * 64 + lg * 16) ^ sw));
                sacc = __builtin_amdgcn_mfma_f32_16x16x32_bf16(kf, qf[kc], sacc, 0, 0, 0);
            }
            st[n] = sacc;
        }
        if (useMask) {
#pragma unroll
            for (int n = 0; n < 4; ++n)
#pragma unroll
                for (int r = 0; r < 4; ++r)
                    st[n][r] += mrow[(size_t)(qw0 + lr) * Ss + kk0 + n * 16 + lg * 4 + r] * INV_SCALE;
        }
        float pmax = st[0][0];
#pragma unroll
        for (int n = 0; n < 4; ++n)
#pragma unroll
            for (int r = 0; r < 4; ++r) pmax = fmaxf(pmax, st[n][r]);
        pmax = fmaxf(pmax, __shfl_xor(pmax, 16));
        pmax = fmaxf(pmax, __shfl_xor(pmax, 32));
        bool need = pmax > mr + RAW_THR;
        if (__any(need)) {
            float mn = fmaxf(mr, pmax);
            float al = fexp2((mr - mn) * CEXP);
            mr = mn;
            lsum *= al;
            float a0 = __shfl(al, lg * 4 + 0), a1 = __shfl(al, lg * 4 + 1);
            float a2 = __shfl(al, lg * 4 + 2), a3 = __shfl(al, lg * 4 + 3);
#pragma unroll
            for (int dn = 0; dn < 8; ++dn) {
                ctxa[dn][0] *= a0; ctxa[dn][1] *= a1; ctxa[dn][2] *= a2; ctxa[dn][3] *= a3;
            }
        }
        float mC = mr * CEXP;
        float rs = 0.f;
        u16x4 pk[4];
#pragma unroll
        for (int n = 0; n < 4; ++n)
#pragma unroll
            for (int r = 0; r < 4; ++r) {
                float p = fexp2(st[n][r] * CEXP - mC);
                rs += p;
                pk[n][r] = f2bf(p);
            }
        rs += __shfl_xor(rs, 16);
        rs += __shfl_xor(rs, 32);
        lsum += rs;
        char* pw = (char*)ldsP[w];
        int swp = (lr & 7) << 4;
#pragma unroll
        for (int n = 0; n < 4; ++n)
            *(u16x4*)(pw + lr * 128 + ((32 * n + 8 * lg) ^ swp)) = pk[n];
        asm volatile("s_waitcnt lgkmcnt(0)" ::: "memory");
        s16x8 pa[2];
#pragma unroll
        for (int c2 = 0; c2 < 2; ++c2)
            pa[c2] = *(const s16x8*)(pw + lr * 128 + ((64 * c2 + 16 * lg) ^ swp));
#pragma unroll
        for (int dn = 0; dn < 8; ++dn) {
            const char* vb = ldsV + (dn * 16 + lr) * 128;
#pragma unroll
            for (int c2 = 0; c2 < 2; ++c2) {
                s16x8 vf = *(const s16x8*)(vb + ((c2 * 64 + lg * 16) ^ swp));
                ctxa[dn] = __builtin_amdgcn_mfma_f32_16x16x32_bf16(pa[c2], vf, ctxa[dn], 0, 0, 0);
            }
        }
    }
    float l0 = 1.f / __shfl(lsum, lg * 4 + 0), l1 = 1.f / __shfl(lsum, lg * 4 + 1);
    float l2 = 1.f / __shfl(lsum, lg * 4 + 2), l3 = 1.f / __shfl(lsum, lg * 4 + 3);
#pragma unroll
    for (int dn = 0; dn < 8; ++dn) {
        size_t base = ((size_t)(b * Ss + qw0)) * Hh + h * 128 + dn * 16 + lr;
        ctxb[base + (size_t)(lg * 4 + 0) * Hh] = f2bf(ctxa[dn][0] * l0);
        ctxb[base + (size_t)(lg * 4 + 1) * Hh] = f2bf(ctxa[dn][1] * l1);
        ctxb[base + (size_t)(lg * 4 + 2) * Hh] = f2bf(ctxa[dn][2] * l2);
        ctxb[base + (size_t)(lg * 4 + 3) * Hh] = f2bf(ctxa[dn][3] * l3);
    }
}

extern "C" void kernel_launch(void* const* d_in, const int* in_sizes, int n_in,
                              void* d_out, int out_size, void* d_ws, size_t ws_size,
                              hipStream_t stream) {
    (void)in_sizes; (void)n_in; (void)out_size; (void)ws_size;
    const float* hidden = (const float*)d_in[0];
    const float* mask   = (const float*)d_in[1];
    const float* Wqkv   = (const float*)d_in[2];
    const float* Wout   = (const float*)d_in[3];
    float* out = (float*)d_out;

    char* ws = (char*)d_ws;
    size_t off = 0;
    auto alloc = [&](size_t bytes) { char* p = ws + off; off += (bytes + 255) & ~(size_t)255; return p; };
    unsigned short* hbf   = (unsigned short*)alloc((size_t)8388608 * 2);   // hidden bf16; later aliased as ctx
    unsigned short* wqkvT = (unsigned short*)alloc((size_t)12582912 * 2);  // (6144,2048)
    unsigned short* woutT = (unsigned short*)alloc((size_t)4194304 * 2);   // (2048,2048)
    unsigned short* qkv   = (unsigned short*)alloc((size_t)25165824 * 2);  // (4096,6144)
    unsigned short* Vt    = (unsigned short*)alloc((size_t)8388608 * 2);   // (32,128,2048)
    int* flag             = (int*)alloc(256);
    unsigned short* ctx = hbf; // alias: hidden bf16 dead after QKV GEMM

    zero_flag_k<<<1, 64, 0, stream>>>(flag);
    scan_mask_k<<<2048, 256, 0, stream>>>(mask, flag);
    convH_k<<<4096, 256, 0, stream>>>(hidden, hbf);
    convT_k<<<dim3(192, 64), 256, 0, stream>>>(Wqkv, wqkvT, 2048, 6144);
    convT_k<<<dim3(64, 64), 256, 0, stream>>>(Wout, woutT, 2048, 2048);
    gemm256_k<0><<<384, 512, 0, stream>>>(hbf, wqkvT, nullptr, qkv, 4096, 6144, 2048);
    vtrans_k<<<dim3(32, 32, 4), 256, 0, stream>>>(qkv, Vt);
    attn_k<<<512, 512, 0, stream>>>(qkv, Vt, mask, ctx, flag);
    gemm_bt_k<1><<<512, 256, 0, stream>>>(ctx, woutT, out, nullptr, 4096, 2048, 2048);
}